// Round 13
// baseline (5166.956 us; speedup 1.0000x reference)
//
#include <hip/hip_runtime.h>
#include <hip/hip_bf16.h>
#include <cstdint>

#define B_ 64
#define T_ 1024
#define I_ 128
#define R_ 2048
#define O_ 256
#define NBLK 256
#define NSLOT 65
#define SLOTB 32768                    // 8 rows x 2048 bf16 x 2B
#define RSTRIDE (NSLOT * SLOTB)        // per-group ring bytes = 2129920

typedef __attribute__((ext_vector_type(8))) __bf16 bf16x8;
typedef __attribute__((ext_vector_type(4))) float f32x4;
typedef __attribute__((ext_vector_type(4))) unsigned int u32x4;
typedef unsigned short u16;
typedef unsigned int u32;
typedef unsigned long long u64;

#define AT_LDR(p) __hip_atomic_load((p), __ATOMIC_RELAXED, __HIP_MEMORY_SCOPE_AGENT)

__device__ __forceinline__ u16 f2bf(float f) {
    u32 u = __builtin_bit_cast(u32, f);
    u32 r = (u + 0x7FFFu + ((u >> 16) & 1u)) >> 16;
    return (u16)r;
}

__device__ __forceinline__ bf16x8 cvt8r(f32x4 a, f32x4 b) {
    union { u16 h[8]; bf16x8 v; } u;
    u.h[0] = f2bf(a[0]); u.h[1] = f2bf(a[1]); u.h[2] = f2bf(a[2]); u.h[3] = f2bf(a[3]);
    u.h[4] = f2bf(b[0]); u.h[5] = f2bf(b[1]); u.h[6] = f2bf(b[2]); u.h[7] = f2bf(b[3]);
    return u.v;
}

__device__ __forceinline__ bf16x8 ldbf8(const u16* p) {
    return *reinterpret_cast<const bf16x8*>(p);
}

// any u16 == 0x7FC0 (bf16 NaN sentinel; tanh output can't be NaN)
__device__ __forceinline__ u32 sentchk(bf16x8 v) {
    u32x4 u = __builtin_bit_cast(u32x4, v);
    u32 b = 0;
    #pragma unroll
    for (int k = 0; k < 4; ++k) {
        b |= (u32)((u[k] >> 16) == 0x7FC0u);
        b |= (u32)((u[k] & 0xFFFFu) == 0x7FC0u);
    }
    return b;
}

// ---- prep kernels -------------------------------------------------------

__global__ void conv_bf16_kernel(const float* __restrict__ src,
                                 u16* __restrict__ dst, int n) {
    int stride = gridDim.x * blockDim.x;
    for (int i = blockIdx.x * blockDim.x + threadIdx.x; i < n; i += stride)
        dst[i] = f2bf(src[i]);
}

__global__ void bias_sum_kernel(const float* __restrict__ a,
                                const float* __restrict__ b,
                                float* __restrict__ c, int n) {
    int i = blockIdx.x * blockDim.x + threadIdx.x;
    if (i < n) c[i] = a[i] + b[i];
}

// ring: 8 groups x 65 slots x 32768B. slot 0 zero (h0), slots 1..64 NaN sentinel
__global__ void ring_init_kernel(u32* __restrict__ ring) {
    const int perg = NSLOT * (SLOTB / 4);     // 532480 u32
    const int total = 8 * perg;
    int stride = gridDim.x * blockDim.x;
    for (int idx = blockIdx.x * blockDim.x + threadIdx.x; idx < total; idx += stride) {
        int within = idx % perg;
        int slot = within / (SLOTB / 4);
        ring[idx] = slot ? 0x7FC07FC0u : 0u;
    }
}

// ---- persistent XCD-local recurrent kernel (bf16) -----------------------
// r12 structure with the VGPR-spill fixed for real: W_res col-tiles 1-3
// live in 96 AGPRs (tied-asm "=a" stash; the arch-VGPR allocator never
// sees them as VGPR pressure). Inner loop copies each fragment back with a
// tied "=v" asm (4x v_accvgpr_read, ~1cy) right before the MFMA intrinsic,
// so compiler hazard handling is preserved. Col-tile 0 stays in LDS
// (8KB/wave, proven r12). ~100 VGPR + 96 AGPR = ~196 unified, no scratch.
__global__ __launch_bounds__(512, 2) void esn_persist(
    const u16* __restrict__ Wrb, const u16* __restrict__ Wib,
    const float* __restrict__ input, const float* __restrict__ bias,
    u16* __restrict__ ring, const u16* __restrict__ zpage,
    u32* __restrict__ cnt, u16* __restrict__ hfinal)
{
    __shared__ char wlds[65536];        // 8 waves x 8 chunks x 64 lanes x 16B
    __shared__ f32x4 red[8][4][64];     // 32768 B
    __shared__ u16 xout[8][64];         // 1024 B
    __shared__ int s_grp, s_ns, s_mode; // total ~97 KB -> 1 block/CU

    const int tid  = threadIdx.x;
    const int lane = tid & 63;
    const int w    = tid >> 6;
    const int lcol = lane & 15;         // B col within tile / A row
    const int lkh  = lane >> 4;         // 0..3
    const int arow = lcol;              // A row 0..15 (8..15 = zero page)

    // ---- hardened two-counter election ----
    if (tid == 0) {
        u32 xcd;
        asm volatile("s_getreg_b32 %0, hwreg(20, 0, 32)" : "=s"(xcd));
        xcd &= 7;
        int slotA = (int)__hip_atomic_fetch_add(&cnt[xcd], 1u, __ATOMIC_RELAXED,
                                                __HIP_MEMORY_SCOPE_AGENT);
        int gslot = (int)__hip_atomic_fetch_add(&cnt[8], 1u, __ATOMIC_ACQ_REL,
                                                __HIP_MEMORY_SCOPE_AGENT);
        while (AT_LDR(&cnt[8]) < 256u) { }
        u32 c[8], tot;
        do {                              // re-read until all adds visible
            tot = 0;
            #pragma unroll
            for (int i = 0; i < 8; ++i) { c[i] = AT_LDR(&cnt[i]); tot += c[i]; }
        } while (tot != 256u);
        int bal = 1;
        #pragma unroll
        for (int i = 0; i < 8; ++i) bal &= (c[i] == 32u);
        s_mode = bal;
        s_grp  = bal ? (int)xcd : (gslot >> 5);
        s_ns   = bal ? (slotA & 31) : (gslot & 31);
    }
    __syncthreads();
    const int grp = s_grp;
    const int ns  = s_ns;
    bool ic = (s_mode == 0);              // mode B: IC path always

    // ---- stage W_res: col-tile 0 -> LDS (wave-local region) ----
    {
        const u16* bp0 = Wrb + (size_t)(ns * 64 + lcol) * R_ + w * 256 + lkh * 8;
        #pragma unroll
        for (int j = 0; j < 8; ++j) {
            *reinterpret_cast<bf16x8*>(wlds + ((size_t)(w * 8 + j) * 64 + lane) * 16)
                = ldbf8(bp0 + j * 32);
        }
    }
    // ---- col-tiles 1-3 -> 96 AGPRs (tied-asm stash; allocator-proof) ----
    bf16x8 wa1[8], wa2[8], wa3[8];
    {
        const u16* bp1 = Wrb + (size_t)(ns * 64 + 16 + lcol) * R_ + w * 256 + lkh * 8;
        const u16* bp2 = Wrb + (size_t)(ns * 64 + 32 + lcol) * R_ + w * 256 + lkh * 8;
        const u16* bp3 = Wrb + (size_t)(ns * 64 + 48 + lcol) * R_ + w * 256 + lkh * 8;
        #pragma unroll
        for (int j = 0; j < 8; ++j) {
            bf16x8 t1 = ldbf8(bp1 + j * 32);
            bf16x8 t2 = ldbf8(bp2 + j * 32);
            bf16x8 t3 = ldbf8(bp3 + j * 32);
            asm("" : "=a"(wa1[j]) : "0"(t1));   // v_accvgpr_write x4, once
            asm("" : "=a"(wa2[j]) : "0"(t2));
            asm("" : "=a"(wa3[j]) : "0"(t3));
        }
    }
    // input-projection W fragments (waves 0-3, tile w)
    bf16x8 wi[4];
    float bs = 0.f;
    if (w < 4) {
        const u16* wp = Wib + (size_t)(ns * 64 + w * 16 + lcol) * I_ + lkh * 8;
        wi[0] = ldbf8(wp);
        wi[1] = ldbf8(wp + 32);
        wi[2] = ldbf8(wp + 64);
        wi[3] = ldbf8(wp + 96);
        bs = bias[ns * 64 + w * 16 + lcol];
    }
    __syncthreads();

    char* ringB = (char*)ring + (size_t)grp * RSTRIDE;
    const char* zb = (const char*)zpage;
    const float* xrow = input + (size_t)(grp * 8 + (arow & 7)) * T_ * I_;
    const char* wl0 = wlds + ((size_t)w * 8 * 64 + lane) * 16;   // my tile-0 base

    #define LOAD8(F)                                                          \
        asm volatile(                                                         \
            "global_load_dwordx4 %0, %8, off " F "\n\t"                       \
            "global_load_dwordx4 %1, %8, off offset:64 " F "\n\t"             \
            "global_load_dwordx4 %2, %8, off offset:128 " F "\n\t"            \
            "global_load_dwordx4 %3, %8, off offset:192 " F "\n\t"            \
            "global_load_dwordx4 %4, %8, off offset:256 " F "\n\t"            \
            "global_load_dwordx4 %5, %8, off offset:320 " F "\n\t"            \
            "global_load_dwordx4 %6, %8, off offset:384 " F "\n\t"            \
            "global_load_dwordx4 %7, %8, off offset:448 " F "\n\t"            \
            "s_waitcnt vmcnt(0)"                                              \
            : "=&v"(h0), "=&v"(h1), "=&v"(h2), "=&v"(h3),                     \
              "=&v"(h4), "=&v"(h5), "=&v"(h6), "=&v"(h7)                      \
            : "v"(Ah)                                                         \
            : "memory")

    int rs = 0;
    for (int t = 0; t < T_; ++t) {
        const int wsl = (rs + 1 == NSLOT) ? 0 : rs + 1;
        const int ps  = (rs == 0) ? NSLOT - 1 : rs - 1;
        const char* slotR = ringB + (size_t)rs  * SLOTB;
        char*       slotW = ringB + (size_t)wsl * SLOTB;
        char*       slotP = ringB + (size_t)ps  * SLOTB;

        // ---- input projection (waves 0-3, tile w; independent of h) ----
        f32x4 facc = {0.f, 0.f, 0.f, 0.f};
        if (w < 4) {
            const float* Ax = xrow + (size_t)t * I_ + lkh * 8;
            const f32x4 z4 = {0.f, 0.f, 0.f, 0.f};
            #pragma unroll
            for (int kc = 0; kc < 4; ++kc) {
                f32x4 xa = z4, xb = z4;
                if (arow < 8) {
                    xa = *reinterpret_cast<const f32x4*>(Ax + kc * 32);
                    xb = *reinterpret_cast<const f32x4*>(Ax + kc * 32 + 4);
                }
                facc = __builtin_amdgcn_mfma_f32_16x16x32_bf16(cvt8r(xa, xb), wi[kc], facc, 0, 0, 0);
            }
        }

        // ---- poll+load h A-fragments (NaN sentinel; rows 8-15 = zero page) ----
        const char* base = (arow < 8) ? (slotR + arow * 4096) : zb;
        const char* Ah = base + (size_t)(w * 256 + lkh * 8) * 2;
        bf16x8 h0, h1, h2, h3, h4, h5, h6, h7;
        {
            u32 bad; int anybad; int spins = 0;
            do {
                if (ic) { LOAD8("sc1"); } else { LOAD8("sc0"); }
                __builtin_amdgcn_sched_barrier(0);
                bad = sentchk(h0) | sentchk(h1) | sentchk(h2) | sentchk(h3) |
                      sentchk(h4) | sentchk(h5) | sentchk(h6) | sentchk(h7);
                anybad = __any((int)bad);
                if (anybad && !ic && ++spins >= 64) ic = true;   // sticky escape
            } while (anybad);
        }

        // ---- recurrent MFMAs: tile0 from LDS; tiles 1-3 from AGPR cache ----
        f32x4 acc0 = {0.f,0.f,0.f,0.f}, acc1 = {0.f,0.f,0.f,0.f};
        f32x4 acc2 = {0.f,0.f,0.f,0.f}, acc3 = {0.f,0.f,0.f,0.f};
        #define RSTEP(J, HJ)                                                      \
        {                                                                         \
            bf16x8 b0 = *reinterpret_cast<const bf16x8*>(wl0 + (J) * 1024);       \
            bf16x8 b1, b2, b3;                                                    \
            asm("" : "=v"(b1) : "0"(wa1[J]));    /* v_accvgpr_read x4 */          \
            asm("" : "=v"(b2) : "0"(wa2[J]));                                     \
            asm("" : "=v"(b3) : "0"(wa3[J]));                                     \
            acc0 = __builtin_amdgcn_mfma_f32_16x16x32_bf16(HJ, b0, acc0, 0, 0, 0); \
            acc1 = __builtin_amdgcn_mfma_f32_16x16x32_bf16(HJ, b1, acc1, 0, 0, 0); \
            acc2 = __builtin_amdgcn_mfma_f32_16x16x32_bf16(HJ, b2, acc2, 0, 0, 0); \
            acc3 = __builtin_amdgcn_mfma_f32_16x16x32_bf16(HJ, b3, acc3, 0, 0, 0); \
        }
        RSTEP(0, h0) RSTEP(1, h1) RSTEP(2, h2) RSTEP(3, h3)
        RSTEP(4, h4) RSTEP(5, h5) RSTEP(6, h6) RSTEP(7, h7)
        #undef RSTEP

        red[w][0][lane] = acc0;
        red[w][1][lane] = acc1;
        red[w][2][lane] = acc2;
        red[w][3][lane] = acc3;
        __syncthreads();                 // b1: all partials visible

        // ---- tail: wave w<4 reduces tile w, adds xin+bias, tanh ----
        if (w < 4) {
            f32x4 tot = red[0][w][lane];
            #pragma unroll
            for (int ww = 1; ww < 8; ++ww) tot += red[ww][w][lane];
            tot += facc;
            #pragma unroll
            for (int i = 0; i < 4; ++i) {
                int orow = lkh * 4 + i;  // C layout: col=lane&15, row=lkh*4+i
                if (orow < 8)
                    xout[orow][w * 16 + lcol] = f2bf(tanhf(tot[i] + bs));
            }
        }
        __syncthreads();                 // b2: xout complete

        if (w == 0) {                    // publish: sc1 write-through
            bf16x8 v = ldbf8(&xout[lane >> 3][(lane & 7) * 8]);
            char* dst = slotW + (size_t)(lane >> 3) * 4096 + ns * 128 + (lane & 7) * 16;
            asm volatile("global_store_dwordx4 %0, %1, off sc1"
                         :: "v"(dst), "v"(v) : "memory");
        }
        if (w == 1) {                    // re-poison slot consumed at t-1
            u32x4 sq = {0x7FC07FC0u, 0x7FC07FC0u, 0x7FC07FC0u, 0x7FC07FC0u};
            char* dst = slotP + (size_t)(lane >> 3) * 4096 + ns * 128 + (lane & 7) * 16;
            asm volatile("global_store_dwordx4 %0, %1, off sc1"
                         :: "v"(dst), "v"(sq) : "memory");
        }
        if (w == 2 && t == T_ - 1) {     // final h -> hfinal (plain stores)
            bf16x8 v = ldbf8(&xout[lane >> 3][(lane & 7) * 8]);
            *reinterpret_cast<bf16x8*>(
                hfinal + (size_t)(grp * 8 + (lane >> 3)) * R_ + ns * 64 + (lane & 7) * 8) = v;
        }
        rs = wsl;
    }
    #undef LOAD8
}

// ---- readout ------------------------------------------------------------
__global__ __launch_bounds__(128) void readout_kernel(
    const u16* __restrict__ h, const u16* __restrict__ Wo,
    const float* __restrict__ b_out, float* __restrict__ out)
{
    const int lane = threadIdx.x & 63;
    const int wid  = threadIdx.x >> 6;
    const int g    = blockIdx.x * 2 + wid;   // 0..63
    const int m    = g >> 4;
    const int n    = g & 15;
    const int koff = (lane >> 4) * 8;
    const int b    = m * 16 + (lane & 15);
    const int col  = n * 16 + (lane & 15);

    f32x4 acc0 = {0.f,0.f,0.f,0.f};
    f32x4 acc1 = {0.f,0.f,0.f,0.f};
    f32x4 acc2 = {0.f,0.f,0.f,0.f};
    f32x4 acc3 = {0.f,0.f,0.f,0.f};

    const u16* Ah = h + (size_t)b * R_ + koff;
    const u16* Bh = Wo + (size_t)col * R_ + koff;
    #pragma unroll 4
    for (int kc = 0; kc < 64; kc += 4) {
        acc0 = __builtin_amdgcn_mfma_f32_16x16x32_bf16(ldbf8(Ah + (kc + 0) * 32), ldbf8(Bh + (kc + 0) * 32), acc0, 0, 0, 0);
        acc1 = __builtin_amdgcn_mfma_f32_16x16x32_bf16(ldbf8(Ah + (kc + 1) * 32), ldbf8(Bh + (kc + 1) * 32), acc1, 0, 0, 0);
        acc2 = __builtin_amdgcn_mfma_f32_16x16x32_bf16(ldbf8(Ah + (kc + 2) * 32), ldbf8(Bh + (kc + 2) * 32), acc2, 0, 0, 0);
        acc3 = __builtin_amdgcn_mfma_f32_16x16x32_bf16(ldbf8(Ah + (kc + 3) * 32), ldbf8(Bh + (kc + 3) * 32), acc3, 0, 0, 0);
    }

    f32x4 s = acc0 + acc1 + acc2 + acc3;
    const float bo = b_out[col];
    #pragma unroll
    for (int i2 = 0; i2 < 4; ++i2) {
        int row = m * 16 + (lane >> 4) * 4 + i2;
        out[(size_t)row * O_ + col] = s[i2] + bo;
    }
}

// ---- launch -------------------------------------------------------------

extern "C" void kernel_launch(void* const* d_in, const int* in_sizes, int n_in,
                              void* d_out, int out_size, void* d_ws, size_t ws_size,
                              hipStream_t stream) {
    const float* in    = (const float*)d_in[0];
    const float* Winw  = (const float*)d_in[1];
    const float* Winb  = (const float*)d_in[2];
    const float* Wresw = (const float*)d_in[3];
    const float* Wresb = (const float*)d_in[4];
    const float* Woutw = (const float*)d_in[5];
    const float* Woutb = (const float*)d_in[6];
    float* out = (float*)d_out;

    char* ws = (char*)d_ws;
    u16*   Wrb    = (u16*)(ws);                    // 2048*2048*2 = 8388608
    u16*   Wib    = (u16*)(ws + 8388608);          // 2048*128*2  = 524288
    u16*   Wob    = (u16*)(ws + 8912896);          // 256*2048*2  = 1048576
    float* bias   = (float*)(ws + 9961472);        // 2048*4      = 8192
    u16*   hfinal = (u16*)(ws + 9969664);          // 64*2048*2   = 262144
    u16*   zpage  = (u16*)(ws + 10231808);         // 4096
    u32*   cnt    = (u32*)(ws + 10235904);         // 64
    u16*   ring   = (u16*)(ws + 10235968);         // 8*65*32768  = 17039360
    // total: 27275328 bytes (~26 MB)

    conv_bf16_kernel<<<2048, 256, 0, stream>>>(Wresw, Wrb, R_ * R_);
    conv_bf16_kernel<<<256, 256, 0, stream>>>(Winw, Wib, R_ * I_);
    conv_bf16_kernel<<<512, 256, 0, stream>>>(Woutw, Wob, O_ * R_);
    bias_sum_kernel<<<8, 256, 0, stream>>>(Winb, Wresb, bias, R_);
    ring_init_kernel<<<4096, 256, 0, stream>>>((u32*)ring);
    hipMemsetAsync(zpage, 0, 4096 + 64, stream);   // zero page + counters

    esn_persist<<<NBLK, 512, 0, stream>>>(Wrb, Wib, in, bias,
                                          ring, zpage, cnt, hfinal);

    readout_kernel<<<32, 128, 0, stream>>>(hfinal, Wob, Woutb, out);
}